// Round 3
// baseline (94.459 us; speedup 1.0000x reference)
//
#include <hip/hip_runtime.h>
#include <math.h>

#define BB 4
#define LL 64
#define DD 64
#define NEG_ -1e9f

__device__ __forceinline__ float rcp_(float x) { return __builtin_amdgcn_rcpf(x); }
__device__ __forceinline__ float fast_sigmoid(float x) { return rcp_(1.0f + __expf(-x)); }
// tanh(x) = 1 - 2/(exp(2x)+1); saturates correctly via exp->inf/0, rcp(inf)=0
__device__ __forceinline__ float fast_tanh(float x) { return fmaf(-2.0f, rcp_(__expf(2.0f * x) + 1.0f), 1.0f); }

// w[b,i,k,e] = sum_d emb[x[b,i]][d] * rel[k][d*DD+e], for k=1..15 (k=0 masked downstream)
__global__ void rel_w_kernel(const int* __restrict__ x,
                             const float* __restrict__ emb,
                             const float* __restrict__ rel,
                             float* __restrict__ w)
{
    const int k = blockIdx.x + 1;   // 1..15
    const int i = blockIdx.y;
    const int b = blockIdx.z;
    const int t = threadIdx.x;
    __shared__ float o_i[DD];
    const int row = x[b * LL + i];
    o_i[t] = emb[row * DD + t];
    __syncthreads();
    const float* m = rel + k * DD * DD + t;   // column t, stride DD
    float a0 = 0.f, a1 = 0.f, a2 = 0.f, a3 = 0.f;
#pragma unroll
    for (int d = 0; d < DD; d += 4) {
        a0 = fmaf(o_i[d + 0], m[(d + 0) * DD], a0);
        a1 = fmaf(o_i[d + 1], m[(d + 1) * DD], a1);
        a2 = fmaf(o_i[d + 2], m[(d + 2) * DD], a2);
        a3 = fmaf(o_i[d + 3], m[(d + 3) * DD], a3);
    }
    w[((b * LL + i) * 16 + k) * DD + t] = (a0 + a1) + (a2 + a3);
}

// Per (b,i): scores -> softmax -> PV -> out-proj -> fused gx = o2@Wih.T + bih
__global__ void attn_kernel(const int* __restrict__ x, const int* __restrict__ r,
                            const float* __restrict__ emb, const float* __restrict__ w,
                            const float* __restrict__ aW, const float* __restrict__ ab,
                            const float* __restrict__ Wih, const float* __restrict__ bih,
                            float* __restrict__ gx)
{
    const int i = blockIdx.x, b = blockIdx.y, t = threadIdx.x;
    __shared__ float o_lds[LL][DD + 1];
    __shared__ float w_lds[16][DD + 1];
    __shared__ float p_lds[LL];
    __shared__ float ao_lds[DD];
    __shared__ float o2_lds[DD];

    for (int j = 0; j < LL; j++) o_lds[j][t] = emb[x[b * LL + j] * DD + t];
    for (int k = 1; k < 16; k++) w_lds[k][t] = w[((b * LL + i) * 16 + k) * DD + t];
    __syncthreads();

    const int rv = r[(b * LL + i) * LL + t];   // relation id for column j=t
    float s = NEG_;
    if (rv > 0) {
        float a0 = 0.f, a1 = 0.f;
#pragma unroll
        for (int e = 0; e < DD; e += 2) {
            a0 = fmaf(w_lds[rv][e + 0], o_lds[t][e + 0], a0);
            a1 = fmaf(w_lds[rv][e + 1], o_lds[t][e + 1], a1);
        }
        s = a0 + a1;
    }
    float mx = s;
    for (int off = 1; off < 64; off <<= 1) mx = fmaxf(mx, __shfl_xor(mx, off, 64));
    float ex = __expf(s - mx);
    float sum = ex;
    for (int off = 1; off < 64; off <<= 1) sum += __shfl_xor(sum, off, 64);
    p_lds[t] = ex / sum;
    __syncthreads();

    float acc = 0.f;   // ao[d=t] = sum_j p[j]*o[j][t]
    for (int j = 0; j < LL; j++) acc = fmaf(p_lds[j], o_lds[j][t], acc);
    ao_lds[t] = acc;
    __syncthreads();

    float acc2 = ab[t];   // o2[d=t]
    const float* wr = aW + t * DD;
    for (int e = 0; e < DD; e++) acc2 = fmaf(ao_lds[e], wr[e], acc2);
    o2_lds[t] = acc2;
    __syncthreads();

#pragma unroll
    for (int m2 = 0; m2 < 3; m2++) {   // gx[g] = sum_e o2[e]*Wih[g,e] + bih[g]
        const int g = m2 * DD + t;
        float a = bih[g];
        const float* wg = Wih + g * DD;
        for (int e = 0; e < DD; e++) a = fmaf(o2_lds[e], wg[e], a);
        gx[(b * LL + i) * 192 + g] = a;
    }
}

// ONE WAVE per batch. h lives one-element-per-lane; broadcast via 1-float LDS
// write + b128 broadcast reads (own-wave ordering, NO barriers in the scan).
// Each lane computes all 3 of its gates: 192 FMAs from register-resident Whh.
__global__ __launch_bounds__(64, 1) void gru_kernel(
    const float* __restrict__ gx, const float* __restrict__ Whh, const float* __restrict__ bhh,
    const float* __restrict__ oWih, const float* __restrict__ oWhh,
    const float* __restrict__ obih, const float* __restrict__ obhh,
    const int* __restrict__ lvec, float* __restrict__ c_ws)
{
    const int b = blockIdx.x, t = threadIdx.x;
    __shared__ float gx_lds[LL][192];      // 48 KB flat
    __shared__ float h_sh[DD];
    __shared__ float o3[LL][DD + 1];       // +1 pad: tail row reads conflict-free
    __shared__ float gx2[LL][4];
    __shared__ float p2[LL];

    // stage gx (this batch): 3072 float4 over 64 lanes = 48 each, coalesced
    {
        const float4* src = (const float4*)(gx + b * LL * 192);
        float4* dst = (float4*)&gx_lds[0][0];
#pragma unroll 4
        for (int f = 0; f < 48; f++) dst[f * 64 + t] = src[f * 64 + t];
    }

    // Whh rows t (r-gate), 64+t (z-gate) interleaved as float2; row 128+t (n-gate)
    float2 wrz[DD];
    float  wn[DD];
    {
        const float4* r0 = (const float4*)(Whh + t * DD);
        const float4* r1 = (const float4*)(Whh + (DD + t) * DD);
        const float4* r2 = (const float4*)(Whh + (2 * DD + t) * DD);
#pragma unroll
        for (int e = 0; e < 16; e++) {
            const float4 a = r0[e], bq = r1[e], c = r2[e];
            wrz[4 * e + 0] = make_float2(a.x, bq.x);
            wrz[4 * e + 1] = make_float2(a.y, bq.y);
            wrz[4 * e + 2] = make_float2(a.z, bq.z);
            wrz[4 * e + 3] = make_float2(a.w, bq.w);
            wn[4 * e + 0] = c.x; wn[4 * e + 1] = c.y;
            wn[4 * e + 2] = c.z; wn[4 * e + 3] = c.w;
        }
    }
    const float br = bhh[t], bz = bhh[DD + t], bn = bhh[2 * DD + t];

    float h = 0.0f;
    h_sh[t] = 0.0f;

#pragma unroll 1
    for (int l = 0; l < LL; l++) {
        // gh dots: broadcast-read h, FMA against register W rows
        float2 a0 = make_float2(0.f, 0.f), a1 = a0, a2 = a0, a3 = a0;
        float n0 = 0.f, n1 = 0.f, n2 = 0.f, n3 = 0.f;
#pragma unroll
        for (int e = 0; e < DD; e += 4) {
            const float4 hv = *(const float4*)&h_sh[e];
            a0.x = fmaf(hv.x, wrz[e + 0].x, a0.x); a0.y = fmaf(hv.x, wrz[e + 0].y, a0.y);
            a1.x = fmaf(hv.y, wrz[e + 1].x, a1.x); a1.y = fmaf(hv.y, wrz[e + 1].y, a1.y);
            a2.x = fmaf(hv.z, wrz[e + 2].x, a2.x); a2.y = fmaf(hv.z, wrz[e + 2].y, a2.y);
            a3.x = fmaf(hv.w, wrz[e + 3].x, a3.x); a3.y = fmaf(hv.w, wrz[e + 3].y, a3.y);
            n0 = fmaf(hv.x, wn[e + 0], n0); n1 = fmaf(hv.y, wn[e + 1], n1);
            n2 = fmaf(hv.z, wn[e + 2], n2); n3 = fmaf(hv.w, wn[e + 3], n3);
        }
        const float hr = br + ((a0.x + a1.x) + (a2.x + a3.x));
        const float hz = bz + ((a0.y + a1.y) + (a2.y + a3.y));
        const float hn = bn + ((n0 + n1) + (n2 + n3));

        const float rg = fast_sigmoid(gx_lds[l][t] + hr);
        const float zg = fast_sigmoid(gx_lds[l][DD + t] + hz);
        const float ng = fast_tanh(gx_lds[l][2 * DD + t] + rg * hn);
        h = (1.0f - zg) * ng + zg * h;
        h_sh[t] = h;       // next iter's broadcast source (own-wave lgkmcnt ordering)
        o3[l][t] = h;
    }
    __syncthreads();   // 1-wave: just a waitcnt drain, cheap

    // output-GRU input projections: lane t handles row l=t (3 dots of 64)
    {
        float A0 = obih[0], A1 = obih[1], A2 = obih[2];
        const float* w0 = oWih;
        const float* w1 = oWih + DD;
        const float* w2 = oWih + 2 * DD;
#pragma unroll 8
        for (int e = 0; e < DD; e++) {
            const float ov = o3[t][e];     // (t+e)%32 banks: conflict-free
            A0 = fmaf(ov, w0[e], A0);
            A1 = fmaf(ov, w1[e], A1);
            A2 = fmaf(ov, w2[e], A2);
        }
        gx2[t][0] = A0; gx2[t][1] = A1; gx2[t][2] = A2;
    }
    __syncthreads();

    // H=1 scan (serial, lane 0) with next-step prefetch
    if (t == 0) {
        const float w0 = oWhh[0], w1 = oWhh[1], w2 = oWhh[2];
        const float c0 = obhh[0], c1 = obhh[1], c2 = obhh[2];
        float hh = 0.0f;
        float g0 = gx2[0][0], g1 = gx2[0][1], g2 = gx2[0][2];
#pragma unroll 1
        for (int l = 0; l < LL; l++) {
            const int ln = (l + 1) & 63;
            const float ng0 = gx2[ln][0], ng1 = gx2[ln][1], ng2 = gx2[ln][2];
            const float rg = fast_sigmoid(g0 + fmaf(hh, w0, c0));
            const float zg = fast_sigmoid(g1 + fmaf(hh, w1, c1));
            const float ng = fast_tanh(g2 + rg * fmaf(hh, w2, c2));
            hh = (1.0f - zg) * ng + zg * hh;
            p2[l] = hh;
            g0 = ng0; g1 = ng1; g2 = ng2;
        }
    }
    __syncthreads();

    // bug-faithful mask: col <= max_b(l[b]); wave softmax
    {
        const int maxl = max(max(lvec[0], lvec[1]), max(lvec[2], lvec[3]));
        const float v = (t <= maxl) ? p2[t] : NEG_;
        float mx = v;
        for (int off = 1; off < 64; off <<= 1) mx = fmaxf(mx, __shfl_xor(mx, off, 64));
        const float ex = __expf(v - mx);
        float sum = ex;
        for (int off = 1; off < 64; off <<= 1) sum += __shfl_xor(sum, off, 64);
        p2[t] = ex * rcp_(sum);
    }
    __syncthreads();

    {   // c[d=t] = sum_l p2[l]*o3[l][t]
        float acc = 0.f;
#pragma unroll 8
        for (int l = 0; l < LL; l++) acc = fmaf(p2[l], o3[l][t], acc);
        c_ws[b * DD + t] = acc;
    }
}

// Classifier + softmax + loss for all batches; writes all 9 outputs
__global__ void cls_kernel(const float* __restrict__ c_ws, const int* __restrict__ y,
                           const float* __restrict__ W1, const float* __restrict__ b1,
                           const float* __restrict__ W2, const float* __restrict__ b2,
                           float* __restrict__ out)
{
    const int t = threadIdx.x;
    __shared__ float c_lds[DD];
    __shared__ float h1[32];
    __shared__ float lg[2];
    float loss = 0.0f;
    for (int b = 0; b < BB; b++) {
        c_lds[t] = c_ws[b * DD + t];
        __syncthreads();
        if (t < 32) {
            float a = b1[t];
            const float* wr = W1 + t * DD;
            for (int d = 0; d < DD; d++) a = fmaf(c_lds[d], wr[d], a);
            h1[t] = fmaxf(a, 0.0f);
        }
        __syncthreads();
        if (t < 2) {
            float a = b2[t];
            const float* wr = W2 + t * 32;
            for (int m2 = 0; m2 < 32; m2++) a = fmaf(h1[m2], wr[m2], a);
            lg[t] = a;
        }
        __syncthreads();
        if (t == 0) {
            const float l0 = lg[0], l1 = lg[1];
            const float mx = fmaxf(l0, l1);
            const float e0 = __expf(l0 - mx), e1 = __expf(l1 - mx);
            const float s = e0 + e1;
            out[b * 2 + 0] = e0 / s;
            out[b * 2 + 1] = e1 / s;
            const float lp = ((y[b] == 1) ? l1 : l0) - mx - __logf(s);
            loss -= lp * 0.25f;
        }
        __syncthreads();
    }
    if (t == 0) out[8] = loss;
}

extern "C" void kernel_launch(void* const* d_in, const int* in_sizes, int n_in,
                              void* d_out, int out_size, void* d_ws, size_t ws_size,
                              hipStream_t stream)
{
    const int*   x    = (const int*)d_in[0];
    const int*   y    = (const int*)d_in[1];
    const int*   r    = (const int*)d_in[2];
    const int*   l    = (const int*)d_in[3];
    const float* emb  = (const float*)d_in[4];
    const float* rel  = (const float*)d_in[5];
    const float* aW   = (const float*)d_in[6];
    const float* ab   = (const float*)d_in[7];
    const float* Wih  = (const float*)d_in[8];
    const float* Whh  = (const float*)d_in[9];
    const float* bih  = (const float*)d_in[10];
    const float* bhh  = (const float*)d_in[11];
    const float* oWih = (const float*)d_in[12];
    const float* oWhh = (const float*)d_in[13];
    const float* obih = (const float*)d_in[14];
    const float* obhh = (const float*)d_in[15];
    const float* W1   = (const float*)d_in[16];
    const float* b1   = (const float*)d_in[17];
    const float* W2   = (const float*)d_in[18];
    const float* b2   = (const float*)d_in[19];

    float* ws  = (float*)d_ws;
    float* w   = ws;                       // B*L*16*D = 262144 floats
    float* gx  = ws + 262144;              // B*L*192  =  49152 floats
    float* cws = ws + 262144 + 49152;      // B*D      =    256 floats

    rel_w_kernel<<<dim3(15, LL, BB), DD, 0, stream>>>(x, emb, rel, w);
    attn_kernel<<<dim3(LL, BB), DD, 0, stream>>>(x, r, emb, w, aW, ab, Wih, bih, gx);
    gru_kernel<<<BB, 64, 0, stream>>>(gx, Whh, bhh, oWih, oWhh, obih, obhh, l, cws);
    cls_kernel<<<1, DD, 0, stream>>>(cws, y, W1, b1, W2, b2, (float*)d_out);
}

// Round 4
// 66.291 us; speedup vs baseline: 1.4249x; 1.4249x over previous
//
#include <hip/hip_runtime.h>
#include <math.h>

#define BB 4
#define LL 64
#define DD 64
#define NEG_ -1e9f

typedef float v2f __attribute__((ext_vector_type(2)));

__device__ __forceinline__ float rcp_(float x) { return __builtin_amdgcn_rcpf(x); }
__device__ __forceinline__ float fast_sigmoid(float x) { return rcp_(1.0f + __expf(-x)); }
// tanh(x) = 1 - 2/(exp(2x)+1); saturates correctly via exp->inf/0, rcp(inf)=0
__device__ __forceinline__ float fast_tanh(float x) { return fmaf(-2.0f, rcp_(__expf(2.0f * x) + 1.0f), 1.0f); }

// w[b,i,k,e] = sum_d emb[x[b,i]][d] * rel[k][d*DD+e], for k=1..15 (k=0 masked downstream)
__global__ void rel_w_kernel(const int* __restrict__ x,
                             const float* __restrict__ emb,
                             const float* __restrict__ rel,
                             float* __restrict__ w)
{
    const int k = blockIdx.x + 1;   // 1..15
    const int i = blockIdx.y;
    const int b = blockIdx.z;
    const int t = threadIdx.x;
    __shared__ float o_i[DD];
    const int row = x[b * LL + i];
    o_i[t] = emb[row * DD + t];
    __syncthreads();
    const float* m = rel + k * DD * DD + t;   // column t, stride DD
    float a0 = 0.f, a1 = 0.f, a2 = 0.f, a3 = 0.f;
#pragma unroll
    for (int d = 0; d < DD; d += 4) {
        a0 = fmaf(o_i[d + 0], m[(d + 0) * DD], a0);
        a1 = fmaf(o_i[d + 1], m[(d + 1) * DD], a1);
        a2 = fmaf(o_i[d + 2], m[(d + 2) * DD], a2);
        a3 = fmaf(o_i[d + 3], m[(d + 3) * DD], a3);
    }
    w[((b * LL + i) * 16 + k) * DD + t] = (a0 + a1) + (a2 + a3);
}

// Per (b,i): scores -> softmax -> PV -> out-proj -> fused gx = o2@Wih.T + bih
__global__ void attn_kernel(const int* __restrict__ x, const int* __restrict__ r,
                            const float* __restrict__ emb, const float* __restrict__ w,
                            const float* __restrict__ aW, const float* __restrict__ ab,
                            const float* __restrict__ Wih, const float* __restrict__ bih,
                            float* __restrict__ gx)
{
    const int i = blockIdx.x, b = blockIdx.y, t = threadIdx.x;
    __shared__ float o_lds[LL][DD + 1];
    __shared__ float w_lds[16][DD + 1];
    __shared__ float p_lds[LL];
    __shared__ float ao_lds[DD];
    __shared__ float o2_lds[DD];

    for (int j = 0; j < LL; j++) o_lds[j][t] = emb[x[b * LL + j] * DD + t];
    for (int k = 1; k < 16; k++) w_lds[k][t] = w[((b * LL + i) * 16 + k) * DD + t];
    __syncthreads();

    const int rv = r[(b * LL + i) * LL + t];   // relation id for column j=t
    float s = NEG_;
    if (rv > 0) {
        float a0 = 0.f, a1 = 0.f;
#pragma unroll
        for (int e = 0; e < DD; e += 2) {
            a0 = fmaf(w_lds[rv][e + 0], o_lds[t][e + 0], a0);
            a1 = fmaf(w_lds[rv][e + 1], o_lds[t][e + 1], a1);
        }
        s = a0 + a1;
    }
    float mx = s;
    for (int off = 1; off < 64; off <<= 1) mx = fmaxf(mx, __shfl_xor(mx, off, 64));
    float ex = __expf(s - mx);
    float sum = ex;
    for (int off = 1; off < 64; off <<= 1) sum += __shfl_xor(sum, off, 64);
    p_lds[t] = ex / sum;
    __syncthreads();

    float acc = 0.f;   // ao[d=t] = sum_j p[j]*o[j][t]
    for (int j = 0; j < LL; j++) acc = fmaf(p_lds[j], o_lds[j][t], acc);
    ao_lds[t] = acc;
    __syncthreads();

    float acc2 = ab[t];   // o2[d=t]
    const float* wr = aW + t * DD;
    for (int e = 0; e < DD; e++) acc2 = fmaf(ao_lds[e], wr[e], acc2);
    o2_lds[t] = acc2;
    __syncthreads();

#pragma unroll
    for (int m2 = 0; m2 < 3; m2++) {   // gx[g] = sum_e o2[e]*Wih[g,e] + bih[g]
        const int g = m2 * DD + t;
        float a = bih[g];
        const float* wg = Wih + g * DD;
        for (int e = 0; e < DD; e++) a = fmaf(o2_lds[e], wg[e], a);
        gx[(b * LL + i) * 192 + g] = a;
    }
}

// ONE WAVE per batch, barrier-free scan. Weights held in ~192 pinned VGPRs
// (asm "+v" pin prevents rematerialization of the loads into the loop).
// Dot products as v2f -> v_pk_fma_f32 (96 pk ops/step instead of 192 fma).
__global__ __launch_bounds__(64, 1) void gru_kernel(
    const float* __restrict__ gx, const float* __restrict__ Whh, const float* __restrict__ bhh,
    const float* __restrict__ oWih, const float* __restrict__ oWhh,
    const float* __restrict__ obih, const float* __restrict__ obhh,
    const int* __restrict__ lvec, float* __restrict__ c_ws)
{
    const int b = blockIdx.x, t = threadIdx.x;
    __shared__ float gx_lds[LL][192];      // 48 KB flat
    __shared__ float h_sh[DD];
    __shared__ float o3[LL][DD + 1];
    __shared__ float gx2[LL][4];
    __shared__ float p2[LL];

    // stage gx (this batch): 3072 float4 over 64 lanes = 48 each, coalesced
    {
        const float4* src = (const float4*)(gx + b * LL * 192);
        float4* dst = (float4*)&gx_lds[0][0];
#pragma unroll 4
        for (int f = 0; f < 48; f++) dst[f * 64 + t] = src[f * 64 + t];
    }

    // Whh rows t (r), 64+t (z), 128+t (n) as 32 v2f each (packed along e)
    v2f wr2[32], wz2[32], wn2[32];
    {
        const float4* r0 = (const float4*)(Whh + t * DD);
        const float4* r1 = (const float4*)(Whh + (DD + t) * DD);
        const float4* r2 = (const float4*)(Whh + (2 * DD + t) * DD);
#pragma unroll
        for (int e = 0; e < 16; e++) {
            const float4 a = r0[e], bq = r1[e], c = r2[e];
            wr2[2 * e + 0] = (v2f){a.x, a.y};  wr2[2 * e + 1] = (v2f){a.z, a.w};
            wz2[2 * e + 0] = (v2f){bq.x, bq.y}; wz2[2 * e + 1] = (v2f){bq.z, bq.w};
            wn2[2 * e + 0] = (v2f){c.x, c.y};  wn2[2 * e + 1] = (v2f){c.z, c.w};
        }
    }
    // Pin: make values opaque so the allocator cannot re-load them in the loop
#pragma unroll
    for (int i2 = 0; i2 < 32; i2++) {
        asm volatile("" : "+v"(wr2[i2]), "+v"(wz2[i2]), "+v"(wn2[i2]));
    }
    const float br = bhh[t], bz = bhh[DD + t], bn = bhh[2 * DD + t];

    float h = 0.0f;
    h_sh[t] = 0.0f;
    const float* gxr = &gx_lds[0][0];

#pragma unroll 1
    for (int l = 0; l < LL; l++) {
        const float g_r = gxr[t], g_z = gxr[DD + t], g_n = gxr[2 * DD + t];
        // gh dots: broadcast-read h (16 x b128), v_pk_fma_f32 against pinned weights
        v2f r0 = (v2f){0.f, 0.f}, r1 = r0, r2 = r0, r3 = r0;
        v2f z0 = r0, z1 = r0, z2 = r0, z3 = r0;
        v2f n0 = r0, n1 = r0, n2 = r0, n3 = r0;
#pragma unroll
        for (int e = 0; e < 16; e += 2) {
            const float4 ha = *(const float4*)&h_sh[4 * e];
            const float4 hb = *(const float4*)&h_sh[4 * e + 4];
            const v2f h0 = (v2f){ha.x, ha.y}, h1 = (v2f){ha.z, ha.w};
            const v2f h2 = (v2f){hb.x, hb.y}, h3 = (v2f){hb.z, hb.w};
            r0 = __builtin_elementwise_fma(h0, wr2[2 * e + 0], r0);
            r1 = __builtin_elementwise_fma(h1, wr2[2 * e + 1], r1);
            r2 = __builtin_elementwise_fma(h2, wr2[2 * e + 2], r2);
            r3 = __builtin_elementwise_fma(h3, wr2[2 * e + 3], r3);
            z0 = __builtin_elementwise_fma(h0, wz2[2 * e + 0], z0);
            z1 = __builtin_elementwise_fma(h1, wz2[2 * e + 1], z1);
            z2 = __builtin_elementwise_fma(h2, wz2[2 * e + 2], z2);
            z3 = __builtin_elementwise_fma(h3, wz2[2 * e + 3], z3);
            n0 = __builtin_elementwise_fma(h0, wn2[2 * e + 0], n0);
            n1 = __builtin_elementwise_fma(h1, wn2[2 * e + 1], n1);
            n2 = __builtin_elementwise_fma(h2, wn2[2 * e + 2], n2);
            n3 = __builtin_elementwise_fma(h3, wn2[2 * e + 3], n3);
        }
        const v2f rs = (r0 + r1) + (r2 + r3);
        const v2f zs = (z0 + z1) + (z2 + z3);
        const v2f ns = (n0 + n1) + (n2 + n3);
        const float hr = br + rs.x + rs.y;
        const float hz = bz + zs.x + zs.y;
        const float hn = bn + ns.x + ns.y;

        const float rg = fast_sigmoid(g_r + hr);
        const float zg = fast_sigmoid(g_z + hz);
        const float ng = fast_tanh(g_n + rg * hn);
        h = (1.0f - zg) * ng + zg * h;
        h_sh[t] = h;       // next iter's broadcast source (own-wave lgkmcnt ordering)
        o3[l][t] = h;
        gxr += 192;
    }
    __syncthreads();   // 1-wave: just a waitcnt drain, cheap

    // output-GRU input projections: lane t handles row l=t (3 dots of 64)
    {
        float A0 = obih[0], A1 = obih[1], A2 = obih[2];
        const float* w0 = oWih;
        const float* w1 = oWih + DD;
        const float* w2 = oWih + 2 * DD;
#pragma unroll 8
        for (int e = 0; e < DD; e++) {
            const float ov = o3[t][e];     // (t+e)%32 banks: conflict-free
            A0 = fmaf(ov, w0[e], A0);
            A1 = fmaf(ov, w1[e], A1);
            A2 = fmaf(ov, w2[e], A2);
        }
        gx2[t][0] = A0; gx2[t][1] = A1; gx2[t][2] = A2;
    }
    __syncthreads();

    // H=1 scan (serial, lane 0) with next-step prefetch
    if (t == 0) {
        const float w0 = oWhh[0], w1 = oWhh[1], w2 = oWhh[2];
        const float c0 = obhh[0], c1 = obhh[1], c2 = obhh[2];
        float hh = 0.0f;
        float g0 = gx2[0][0], g1 = gx2[0][1], g2 = gx2[0][2];
#pragma unroll 1
        for (int l = 0; l < LL; l++) {
            const int ln = (l + 1) & 63;
            const float ng0 = gx2[ln][0], ng1 = gx2[ln][1], ng2 = gx2[ln][2];
            const float rg = fast_sigmoid(g0 + fmaf(hh, w0, c0));
            const float zg = fast_sigmoid(g1 + fmaf(hh, w1, c1));
            const float ng = fast_tanh(g2 + rg * fmaf(hh, w2, c2));
            hh = (1.0f - zg) * ng + zg * hh;
            p2[l] = hh;
            g0 = ng0; g1 = ng1; g2 = ng2;
        }
    }
    __syncthreads();

    // bug-faithful mask: col <= max_b(l[b]); wave softmax
    {
        const int maxl = max(max(lvec[0], lvec[1]), max(lvec[2], lvec[3]));
        const float v = (t <= maxl) ? p2[t] : NEG_;
        float mx = v;
        for (int off = 1; off < 64; off <<= 1) mx = fmaxf(mx, __shfl_xor(mx, off, 64));
        const float ex = __expf(v - mx);
        float sum = ex;
        for (int off = 1; off < 64; off <<= 1) sum += __shfl_xor(sum, off, 64);
        p2[t] = ex * rcp_(sum);
    }
    __syncthreads();

    {   // c[d=t] = sum_l p2[l]*o3[l][t]
        float acc = 0.f;
#pragma unroll 8
        for (int l = 0; l < LL; l++) acc = fmaf(p2[l], o3[l][t], acc);
        c_ws[b * DD + t] = acc;
    }
}

// Classifier + softmax + loss for all batches; writes all 9 outputs
__global__ void cls_kernel(const float* __restrict__ c_ws, const int* __restrict__ y,
                           const float* __restrict__ W1, const float* __restrict__ b1,
                           const float* __restrict__ W2, const float* __restrict__ b2,
                           float* __restrict__ out)
{
    const int t = threadIdx.x;
    __shared__ float c_lds[DD];
    __shared__ float h1[32];
    __shared__ float lg[2];
    float loss = 0.0f;
    for (int b = 0; b < BB; b++) {
        c_lds[t] = c_ws[b * DD + t];
        __syncthreads();
        if (t < 32) {
            float a = b1[t];
            const float* wr = W1 + t * DD;
            for (int d = 0; d < DD; d++) a = fmaf(c_lds[d], wr[d], a);
            h1[t] = fmaxf(a, 0.0f);
        }
        __syncthreads();
        if (t < 2) {
            float a = b2[t];
            const float* wr = W2 + t * 32;
            for (int m2 = 0; m2 < 32; m2++) a = fmaf(h1[m2], wr[m2], a);
            lg[t] = a;
        }
        __syncthreads();
        if (t == 0) {
            const float l0 = lg[0], l1 = lg[1];
            const float mx = fmaxf(l0, l1);
            const float e0 = __expf(l0 - mx), e1 = __expf(l1 - mx);
            const float s = e0 + e1;
            out[b * 2 + 0] = e0 / s;
            out[b * 2 + 1] = e1 / s;
            const float lp = ((y[b] == 1) ? l1 : l0) - mx - __logf(s);
            loss -= lp * 0.25f;
        }
        __syncthreads();
    }
    if (t == 0) out[8] = loss;
}

extern "C" void kernel_launch(void* const* d_in, const int* in_sizes, int n_in,
                              void* d_out, int out_size, void* d_ws, size_t ws_size,
                              hipStream_t stream)
{
    const int*   x    = (const int*)d_in[0];
    const int*   y    = (const int*)d_in[1];
    const int*   r    = (const int*)d_in[2];
    const int*   l    = (const int*)d_in[3];
    const float* emb  = (const float*)d_in[4];
    const float* rel  = (const float*)d_in[5];
    const float* aW   = (const float*)d_in[6];
    const float* ab   = (const float*)d_in[7];
    const float* Wih  = (const float*)d_in[8];
    const float* Whh  = (const float*)d_in[9];
    const float* bih  = (const float*)d_in[10];
    const float* bhh  = (const float*)d_in[11];
    const float* oWih = (const float*)d_in[12];
    const float* oWhh = (const float*)d_in[13];
    const float* obih = (const float*)d_in[14];
    const float* obhh = (const float*)d_in[15];
    const float* W1   = (const float*)d_in[16];
    const float* b1   = (const float*)d_in[17];
    const float* W2   = (const float*)d_in[18];
    const float* b2   = (const float*)d_in[19];

    float* ws  = (float*)d_ws;
    float* w   = ws;                       // B*L*16*D = 262144 floats
    float* gx  = ws + 262144;              // B*L*192  =  49152 floats
    float* cws = ws + 262144 + 49152;      // B*D      =    256 floats

    rel_w_kernel<<<dim3(15, LL, BB), DD, 0, stream>>>(x, emb, rel, w);
    attn_kernel<<<dim3(LL, BB), DD, 0, stream>>>(x, r, emb, w, aW, ab, Wih, bih, gx);
    gru_kernel<<<BB, 64, 0, stream>>>(gx, Whh, bhh, oWih, oWhh, obih, obhh, l, cws);
    cls_kernel<<<1, DD, 0, stream>>>(cws, y, W1, b1, W2, b2, (float*)d_out);
}

// Round 5
// 65.004 us; speedup vs baseline: 1.4531x; 1.0198x over previous
//
#include <hip/hip_runtime.h>
#include <math.h>

#define BB 4
#define LL 64
#define DD 64
#define NEG_ -1e9f

typedef _Float16 h2 __attribute__((ext_vector_type(2)));

__device__ __forceinline__ float rcp_(float x) { return __builtin_amdgcn_rcpf(x); }
__device__ __forceinline__ float fast_sigmoid(float x) { return rcp_(1.0f + __expf(-x)); }
// tanh(x) = 1 - 2/(exp(2x)+1); saturates correctly via exp->inf/0, rcp(inf)=0
__device__ __forceinline__ float fast_tanh(float x) { return fmaf(-2.0f, rcp_(__expf(2.0f * x) + 1.0f), 1.0f); }

// Fused: per (b,i) block computes w[k][e] = sum_d o_i[d]*rel[k][d,e] inline
// (k=1..15, 15 reg accumulators, coalesced rel loads, rel is L2-resident),
// then scores -> softmax -> PV -> out-proj -> gx = o2@Wih.T + bih.
__global__ void attn_kernel(const int* __restrict__ x, const int* __restrict__ r,
                            const float* __restrict__ emb, const float* __restrict__ rel,
                            const float* __restrict__ aW, const float* __restrict__ ab,
                            const float* __restrict__ Wih, const float* __restrict__ bih,
                            float* __restrict__ gx)
{
    const int i = blockIdx.x, b = blockIdx.y, t = threadIdx.x;
    __shared__ float o_lds[LL][DD + 1];
    __shared__ float w_lds[16][DD + 1];
    __shared__ float p_lds[LL];
    __shared__ float ao_lds[DD];
    __shared__ float o2_lds[DD];

    for (int j = 0; j < LL; j++) o_lds[j][t] = emb[x[b * LL + j] * DD + t];
    __syncthreads();

    // w-phase: lane t accumulates w[k][t] for k=1..15 in registers
    {
        float acc[15];
#pragma unroll
        for (int k = 0; k < 15; k++) acc[k] = 0.0f;
        const float* relc = rel + 4096 + t;   // rel[k+1][d*64+t]
#pragma unroll 2
        for (int d = 0; d < DD; d++) {
            const float od = o_lds[i][d];     // uniform LDS broadcast
#pragma unroll
            for (int k = 0; k < 15; k++)
                acc[k] = fmaf(od, relc[k * 4096 + d * 64], acc[k]);
        }
#pragma unroll
        for (int k = 0; k < 15; k++) w_lds[k + 1][t] = acc[k];
    }
    __syncthreads();

    const int rv = r[(b * LL + i) * LL + t];   // relation id for column j=t
    float s = NEG_;
    if (rv > 0) {
        float a0 = 0.f, a1 = 0.f;
#pragma unroll
        for (int e = 0; e < DD; e += 2) {
            a0 = fmaf(w_lds[rv][e + 0], o_lds[t][e + 0], a0);
            a1 = fmaf(w_lds[rv][e + 1], o_lds[t][e + 1], a1);
        }
        s = a0 + a1;
    }
    float mx = s;
    for (int off = 1; off < 64; off <<= 1) mx = fmaxf(mx, __shfl_xor(mx, off, 64));
    float ex = __expf(s - mx);
    float sum = ex;
    for (int off = 1; off < 64; off <<= 1) sum += __shfl_xor(sum, off, 64);
    p_lds[t] = ex / sum;
    __syncthreads();

    float acc = 0.f;   // ao[d=t] = sum_j p[j]*o[j][t]
    for (int j = 0; j < LL; j++) acc = fmaf(p_lds[j], o_lds[j][t], acc);
    ao_lds[t] = acc;
    __syncthreads();

    float acc2 = ab[t];   // o2[d=t]
    const float* wr = aW + t * DD;
    for (int e = 0; e < DD; e++) acc2 = fmaf(ao_lds[e], wr[e], acc2);
    o2_lds[t] = acc2;
    __syncthreads();

#pragma unroll
    for (int m2 = 0; m2 < 3; m2++) {   // gx[g] = sum_e o2[e]*Wih[g,e] + bih[g]
        const int g = m2 * DD + t;
        float a = bih[g];
        const float* wg = Wih + g * DD;
        for (int e = 0; e < DD; e++) a = fmaf(o2_lds[e], wg[e], a);
        gx[(b * LL + i) * 192 + g] = a;
    }
}

// ONE WAVE per batch, barrier-free scan. Whh held as 96 packed-f16 VGPRs;
// dot via v_dot2_f32_f16 (f32 accumulate). h broadcast as f16: 1 ds_write_b16
// + 8 ds_read_b128 per step. Total live regs ~140 -> arch-VGPR resident.
__global__ __launch_bounds__(64, 1) void gru_kernel(
    const float* __restrict__ gx, const float* __restrict__ Whh, const float* __restrict__ bhh,
    const float* __restrict__ oWih, const float* __restrict__ oWhh,
    const float* __restrict__ obih, const float* __restrict__ obhh,
    const int* __restrict__ lvec, float* __restrict__ c_ws)
{
    const int b = blockIdx.x, t = threadIdx.x;
    __shared__ float gx_lds[LL][192];      // 48 KB flat
    __shared__ _Float16 h16[DD] __attribute__((aligned(16)));
    __shared__ float o3[LL][DD + 1];
    __shared__ float gx2[LL][4];
    __shared__ float p2[LL];

    // stage gx (this batch): 3072 float4 over 64 lanes = 48 each, coalesced
    {
        const float4* src = (const float4*)(gx + b * LL * 192);
        float4* dst = (float4*)&gx_lds[0][0];
#pragma unroll 4
        for (int f = 0; f < 48; f++) dst[f * 64 + t] = src[f * 64 + t];
    }

    // Whh rows t (r), 64+t (z), 128+t (n) as 32 packed-f16 pairs each
    h2 whr[32], whz[32], whn[32];
    {
        const float4* r0 = (const float4*)(Whh + t * DD);
        const float4* r1 = (const float4*)(Whh + (DD + t) * DD);
        const float4* r2 = (const float4*)(Whh + (2 * DD + t) * DD);
#pragma unroll
        for (int e = 0; e < 16; e++) {
            const float4 a = r0[e], bq = r1[e], c = r2[e];
            whr[2 * e + 0] = (h2){(_Float16)a.x, (_Float16)a.y};
            whr[2 * e + 1] = (h2){(_Float16)a.z, (_Float16)a.w};
            whz[2 * e + 0] = (h2){(_Float16)bq.x, (_Float16)bq.y};
            whz[2 * e + 1] = (h2){(_Float16)bq.z, (_Float16)bq.w};
            whn[2 * e + 0] = (h2){(_Float16)c.x, (_Float16)c.y};
            whn[2 * e + 1] = (h2){(_Float16)c.z, (_Float16)c.w};
        }
    }
    // Pin: keep values opaque so they stay resident (no remat into the loop)
#pragma unroll
    for (int i2 = 0; i2 < 32; i2++) {
        asm volatile("" : "+v"(whr[i2]), "+v"(whz[i2]), "+v"(whn[i2]));
    }
    const float br = bhh[t], bz = bhh[DD + t], bn = bhh[2 * DD + t];

    float h = 0.0f;
    h16[t] = (_Float16)0.0f;
    const float* gxr = &gx_lds[0][0];

#pragma unroll 1
    for (int l = 0; l < LL; l++) {
        const float g_r = gxr[t], g_z = gxr[DD + t], g_n = gxr[2 * DD + t];
        float ra0 = 0.f, ra1 = 0.f, ra2 = 0.f, ra3 = 0.f;
        float za0 = 0.f, za1 = 0.f, za2 = 0.f, za3 = 0.f;
        float na0 = 0.f, na1 = 0.f, na2 = 0.f, na3 = 0.f;
#pragma unroll
        for (int j = 0; j < 8; j++) {
            union { float4 f4; h2 hh[4]; } u;
            u.f4 = *(const float4*)&h16[8 * j];   // broadcast (uniform addr)
            ra0 = __builtin_amdgcn_fdot2(u.hh[0], whr[4 * j + 0], ra0, false);
            ra1 = __builtin_amdgcn_fdot2(u.hh[1], whr[4 * j + 1], ra1, false);
            ra2 = __builtin_amdgcn_fdot2(u.hh[2], whr[4 * j + 2], ra2, false);
            ra3 = __builtin_amdgcn_fdot2(u.hh[3], whr[4 * j + 3], ra3, false);
            za0 = __builtin_amdgcn_fdot2(u.hh[0], whz[4 * j + 0], za0, false);
            za1 = __builtin_amdgcn_fdot2(u.hh[1], whz[4 * j + 1], za1, false);
            za2 = __builtin_amdgcn_fdot2(u.hh[2], whz[4 * j + 2], za2, false);
            za3 = __builtin_amdgcn_fdot2(u.hh[3], whz[4 * j + 3], za3, false);
            na0 = __builtin_amdgcn_fdot2(u.hh[0], whn[4 * j + 0], na0, false);
            na1 = __builtin_amdgcn_fdot2(u.hh[1], whn[4 * j + 1], na1, false);
            na2 = __builtin_amdgcn_fdot2(u.hh[2], whn[4 * j + 2], na2, false);
            na3 = __builtin_amdgcn_fdot2(u.hh[3], whn[4 * j + 3], na3, false);
        }
        const float hr = br + ((ra0 + ra1) + (ra2 + ra3));
        const float hz = bz + ((za0 + za1) + (za2 + za3));
        const float hn = bn + ((na0 + na1) + (na2 + na3));

        const float rg = fast_sigmoid(g_r + hr);
        const float zg = fast_sigmoid(g_z + hz);
        const float ng = fast_tanh(g_n + rg * hn);
        h = (1.0f - zg) * ng + zg * h;
        h16[t] = (_Float16)h;   // next iter's broadcast source (own-wave ordering)
        o3[l][t] = h;
        gxr += 192;
    }
    __syncthreads();   // 1-wave: just a waitcnt drain, cheap

    // output-GRU input projections: lane t handles row l=t (3 dots of 64)
    {
        float A0 = obih[0], A1 = obih[1], A2 = obih[2];
        const float* w0 = oWih;
        const float* w1 = oWih + DD;
        const float* w2 = oWih + 2 * DD;
#pragma unroll 8
        for (int e = 0; e < DD; e++) {
            const float ov = o3[t][e];     // (t+e)%32 banks: conflict-free
            A0 = fmaf(ov, w0[e], A0);
            A1 = fmaf(ov, w1[e], A1);
            A2 = fmaf(ov, w2[e], A2);
        }
        gx2[t][0] = A0; gx2[t][1] = A1; gx2[t][2] = A2;
    }
    __syncthreads();

    // H=1 scan (serial, lane 0) with next-step prefetch
    if (t == 0) {
        const float w0 = oWhh[0], w1 = oWhh[1], w2 = oWhh[2];
        const float c0 = obhh[0], c1 = obhh[1], c2 = obhh[2];
        float hh = 0.0f;
        float g0 = gx2[0][0], g1 = gx2[0][1], g2 = gx2[0][2];
#pragma unroll 1
        for (int l = 0; l < LL; l++) {
            const int ln = (l + 1) & 63;
            const float ng0 = gx2[ln][0], ng1 = gx2[ln][1], ng2 = gx2[ln][2];
            const float rg = fast_sigmoid(g0 + fmaf(hh, w0, c0));
            const float zg = fast_sigmoid(g1 + fmaf(hh, w1, c1));
            const float ng = fast_tanh(g2 + rg * fmaf(hh, w2, c2));
            hh = (1.0f - zg) * ng + zg * hh;
            p2[l] = hh;
            g0 = ng0; g1 = ng1; g2 = ng2;
        }
    }
    __syncthreads();

    // bug-faithful mask: col <= max_b(l[b]); wave softmax
    {
        const int maxl = max(max(lvec[0], lvec[1]), max(lvec[2], lvec[3]));
        const float v = (t <= maxl) ? p2[t] : NEG_;
        float mx = v;
        for (int off = 1; off < 64; off <<= 1) mx = fmaxf(mx, __shfl_xor(mx, off, 64));
        const float ex = __expf(v - mx);
        float sum = ex;
        for (int off = 1; off < 64; off <<= 1) sum += __shfl_xor(sum, off, 64);
        p2[t] = ex * rcp_(sum);
    }
    __syncthreads();

    {   // c[d=t] = sum_l p2[l]*o3[l][t]
        float acc = 0.f;
#pragma unroll 8
        for (int l = 0; l < LL; l++) acc = fmaf(p2[l], o3[l][t], acc);
        c_ws[b * DD + t] = acc;
    }
}

// Classifier + softmax + loss for all batches; writes all 9 outputs
__global__ void cls_kernel(const float* __restrict__ c_ws, const int* __restrict__ y,
                           const float* __restrict__ W1, const float* __restrict__ b1,
                           const float* __restrict__ W2, const float* __restrict__ b2,
                           float* __restrict__ out)
{
    const int t = threadIdx.x;
    __shared__ float c_lds[DD];
    __shared__ float h1[32];
    __shared__ float lg[2];
    float loss = 0.0f;
    for (int b = 0; b < BB; b++) {
        c_lds[t] = c_ws[b * DD + t];
        __syncthreads();
        if (t < 32) {
            float a = b1[t];
            const float* wr = W1 + t * DD;
            for (int d = 0; d < DD; d++) a = fmaf(c_lds[d], wr[d], a);
            h1[t] = fmaxf(a, 0.0f);
        }
        __syncthreads();
        if (t < 2) {
            float a = b2[t];
            const float* wr = W2 + t * 32;
            for (int m2 = 0; m2 < 32; m2++) a = fmaf(h1[m2], wr[m2], a);
            lg[t] = a;
        }
        __syncthreads();
        if (t == 0) {
            const float l0 = lg[0], l1 = lg[1];
            const float mx = fmaxf(l0, l1);
            const float e0 = __expf(l0 - mx), e1 = __expf(l1 - mx);
            const float s = e0 + e1;
            out[b * 2 + 0] = e0 / s;
            out[b * 2 + 1] = e1 / s;
            const float lp = ((y[b] == 1) ? l1 : l0) - mx - __logf(s);
            loss -= lp * 0.25f;
        }
        __syncthreads();
    }
    if (t == 0) out[8] = loss;
}

extern "C" void kernel_launch(void* const* d_in, const int* in_sizes, int n_in,
                              void* d_out, int out_size, void* d_ws, size_t ws_size,
                              hipStream_t stream)
{
    const int*   x    = (const int*)d_in[0];
    const int*   y    = (const int*)d_in[1];
    const int*   r    = (const int*)d_in[2];
    const int*   l    = (const int*)d_in[3];
    const float* emb  = (const float*)d_in[4];
    const float* rel  = (const float*)d_in[5];
    const float* aW   = (const float*)d_in[6];
    const float* ab   = (const float*)d_in[7];
    const float* Wih  = (const float*)d_in[8];
    const float* Whh  = (const float*)d_in[9];
    const float* bih  = (const float*)d_in[10];
    const float* bhh  = (const float*)d_in[11];
    const float* oWih = (const float*)d_in[12];
    const float* oWhh = (const float*)d_in[13];
    const float* obih = (const float*)d_in[14];
    const float* obhh = (const float*)d_in[15];
    const float* W1   = (const float*)d_in[16];
    const float* b1   = (const float*)d_in[17];
    const float* W2   = (const float*)d_in[18];
    const float* b2   = (const float*)d_in[19];

    float* ws  = (float*)d_ws;
    float* gx  = ws;                       // B*L*192 = 49152 floats
    float* cws = ws + 49152;               // B*D     =   256 floats

    attn_kernel<<<dim3(LL, BB), DD, 0, stream>>>(x, r, emb, rel, aW, ab, Wih, bih, gx);
    gru_kernel<<<BB, 64, 0, stream>>>(gx, Whh, bhh, oWih, oWhh, obih, obhh, l, cws);
    cls_kernel<<<1, DD, 0, stream>>>(cws, y, W1, b1, W2, b2, (float*)d_out);
}

// Round 6
// 54.645 us; speedup vs baseline: 1.7286x; 1.1896x over previous
//
#include <hip/hip_runtime.h>
#include <math.h>

#define BB 4
#define LL 64
#define DD 64
#define NEG_ -1e9f

typedef _Float16 h2 __attribute__((ext_vector_type(2)));

__device__ __forceinline__ float rcp_(float x) { return __builtin_amdgcn_rcpf(x); }
__device__ __forceinline__ float fast_sigmoid(float x) { return rcp_(1.0f + __expf(-x)); }
// tanh(x) = 1 - 2/(exp(2x)+1); saturates correctly via exp->inf/0, rcp(inf)=0
__device__ __forceinline__ float fast_tanh(float x) { return fmaf(-2.0f, rcp_(__expf(2.0f * x) + 1.0f), 1.0f); }

// 4-wave attn: w-phase split over waves (k) and lanes (e-quad x d-offset) with
// float4 rel loads + shfl_xor d-reduce. Then scores/softmax (wave0), PV (all
// waves), out-proj + gx-proj (all 256 threads). Also zeroes the gru/cls counter.
__global__ __launch_bounds__(256) void attn_kernel(
    const int* __restrict__ x, const int* __restrict__ r,
    const float* __restrict__ emb, const float* __restrict__ rel,
    const float* __restrict__ aW, const float* __restrict__ ab,
    const float* __restrict__ Wih, const float* __restrict__ bih,
    float* __restrict__ gx, unsigned int* __restrict__ counter)
{
    const int i = blockIdx.x, b = blockIdx.y;
    const int tt = threadIdx.x, lane = tt & 63, wv = tt >> 6;
    __shared__ float o_lds[LL][DD + 1];
    __shared__ float w_lds[16][DD + 1];
    __shared__ float p_lds[LL];
    __shared__ float pv_part[4][DD];
    __shared__ float ao_lds[DD];
    __shared__ float o2_lds[DD];

    if (i == 0 && b == 0 && tt == 0) *counter = 0;   // handoff counter for gru+cls

    // stage o: thread covers row j=tt>>2, floats q*16..q*16+15 (coalesced float4)
    {
        const int j = tt >> 2, q = tt & 3;
        const int row = x[b * LL + j];
        const float4* src = (const float4*)(emb + row * DD + q * 16);
        const float4 v0 = src[0], v1 = src[1], v2 = src[2], v3 = src[3];
        float* dst = &o_lds[j][q * 16];
        dst[0] = v0.x; dst[1] = v0.y; dst[2] = v0.z; dst[3] = v0.w;
        dst[4] = v1.x; dst[5] = v1.y; dst[6] = v1.z; dst[7] = v1.w;
        dst[8] = v2.x; dst[9] = v2.y; dst[10] = v2.z; dst[11] = v2.w;
        dst[12] = v3.x; dst[13] = v3.y; dst[14] = v3.z; dst[15] = v3.w;
    }
    __syncthreads();

    // w-phase: wave wv handles k = wv*4+1 .. wv*4+4 (<=15).
    // lane = (dq=lane>>4, eq=lane&15): partial over d in {g*4+dq}, e-range eq*4..+3
    {
        const int eq = lane & 15, dq = lane >> 4;
#pragma unroll
        for (int kk = 0; kk < 4; kk++) {
            const int k = wv * 4 + kk + 1;
            if (k <= 15) {
                float4 acc = make_float4(0.f, 0.f, 0.f, 0.f);
                const float* relb = rel + k * 4096 + eq * 4;
#pragma unroll
                for (int g2 = 0; g2 < 16; g2++) {
                    const int d = g2 * 4 + dq;
                    const float od = o_lds[i][d];
                    const float4 rv4 = *(const float4*)(relb + d * 64);
                    acc.x = fmaf(od, rv4.x, acc.x);
                    acc.y = fmaf(od, rv4.y, acc.y);
                    acc.z = fmaf(od, rv4.z, acc.z);
                    acc.w = fmaf(od, rv4.w, acc.w);
                }
                acc.x += __shfl_xor(acc.x, 16, 64); acc.y += __shfl_xor(acc.y, 16, 64);
                acc.z += __shfl_xor(acc.z, 16, 64); acc.w += __shfl_xor(acc.w, 16, 64);
                acc.x += __shfl_xor(acc.x, 32, 64); acc.y += __shfl_xor(acc.y, 32, 64);
                acc.z += __shfl_xor(acc.z, 32, 64); acc.w += __shfl_xor(acc.w, 32, 64);
                if (dq == 0) {
                    float* wd = &w_lds[k][eq * 4];
                    wd[0] = acc.x; wd[1] = acc.y; wd[2] = acc.z; wd[3] = acc.w;
                }
            }
        }
    }
    __syncthreads();

    // scores + softmax over j: wave 0 (lane = j)
    if (wv == 0) {
        const int rv = r[(b * LL + i) * LL + lane];
        float s = NEG_;
        if (rv > 0) {
            float a0 = 0.f, a1 = 0.f;
#pragma unroll
            for (int e = 0; e < DD; e += 2) {
                a0 = fmaf(w_lds[rv][e + 0], o_lds[lane][e + 0], a0);
                a1 = fmaf(w_lds[rv][e + 1], o_lds[lane][e + 1], a1);
            }
            s = a0 + a1;
        }
        float mx = s;
        for (int off = 1; off < 64; off <<= 1) mx = fmaxf(mx, __shfl_xor(mx, off, 64));
        const float ex = __expf(s - mx);
        float sum = ex;
        for (int off = 1; off < 64; off <<= 1) sum += __shfl_xor(sum, off, 64);
        p_lds[lane] = ex * rcp_(sum);
    }
    __syncthreads();

    // PV: wave wv sums its 16 j's; lane = d
    {
        float acc = 0.f;
#pragma unroll
        for (int j = 0; j < 16; j++) {
            const int jj = wv * 16 + j;
            acc = fmaf(p_lds[jj], o_lds[jj][lane], acc);
        }
        pv_part[wv][lane] = acc;
    }
    __syncthreads();
    if (wv == 0)
        ao_lds[lane] = (pv_part[0][lane] + pv_part[1][lane]) + (pv_part[2][lane] + pv_part[3][lane]);
    __syncthreads();

    // o2: 4 threads per output row (row=tt>>2, q=tt&3 covers e=q*16..+15)
    {
        const int row = tt >> 2, q = tt & 3;
        float a = 0.f;
        const float4* wr4 = (const float4*)(aW + row * DD + q * 16);
#pragma unroll
        for (int e4 = 0; e4 < 4; e4++) {
            const float4 w4 = wr4[e4];
            const float* av = &ao_lds[q * 16 + e4 * 4];
            a = fmaf(av[0], w4.x, a); a = fmaf(av[1], w4.y, a);
            a = fmaf(av[2], w4.z, a); a = fmaf(av[3], w4.w, a);
        }
        a += __shfl_xor(a, 1, 64);
        a += __shfl_xor(a, 2, 64);
        if (q == 0) o2_lds[row] = a + ab[row];
    }
    __syncthreads();

    // gx: threads 0..191, g = tt: gx[g] = sum_e o2[e]*Wih[g,e] + bih[g]
    if (tt < 192) {
        float a = bih[tt];
        const float4* wg4 = (const float4*)(Wih + tt * DD);
#pragma unroll 4
        for (int e4 = 0; e4 < 16; e4++) {
            const float4 w4 = wg4[e4];
            const float* ov = &o2_lds[e4 * 4];
            a = fmaf(ov[0], w4.x, a); a = fmaf(ov[1], w4.y, a);
            a = fmaf(ov[2], w4.z, a); a = fmaf(ov[3], w4.w, a);
        }
        gx[(b * LL + i) * 192 + tt] = a;
    }
}

// ONE WAVE per batch, barrier-free scan (R5 structure). Whh as 96 packed-f16
// VGPRs, v_dot2_f32_f16 dots, f16 h broadcast via LDS. The last block to
// finish (device-scope atomic counter) runs the classifier inline.
__global__ __launch_bounds__(64, 1) void gru_kernel(
    const float* __restrict__ gx, const float* __restrict__ Whh, const float* __restrict__ bhh,
    const float* __restrict__ oWih, const float* __restrict__ oWhh,
    const float* __restrict__ obih, const float* __restrict__ obhh,
    const int* __restrict__ lvec, float* __restrict__ cws,
    unsigned int* __restrict__ counter, const int* __restrict__ y,
    const float* __restrict__ W1, const float* __restrict__ b1,
    const float* __restrict__ W2, const float* __restrict__ b2,
    float* __restrict__ out)
{
    const int b = blockIdx.x, t = threadIdx.x;
    __shared__ float gx_lds[LL][192];      // 48 KB flat
    __shared__ _Float16 h16[DD] __attribute__((aligned(16)));
    __shared__ float o3[LL][DD + 1];
    __shared__ float gx2[LL][4];
    __shared__ float p2[LL];
    __shared__ float c_lds[DD];
    __shared__ float h1[32];
    __shared__ float lg[2];
    __shared__ unsigned int is_last;

    // stage gx (this batch): 3072 float4 over 64 lanes = 48 each, coalesced
    {
        const float4* src = (const float4*)(gx + b * LL * 192);
        float4* dst = (float4*)&gx_lds[0][0];
#pragma unroll 4
        for (int f = 0; f < 48; f++) dst[f * 64 + t] = src[f * 64 + t];
    }

    // Whh rows t (r), 64+t (z), 128+t (n) as 32 packed-f16 pairs each
    h2 whr[32], whz[32], whn[32];
    {
        const float4* r0 = (const float4*)(Whh + t * DD);
        const float4* r1 = (const float4*)(Whh + (DD + t) * DD);
        const float4* r2 = (const float4*)(Whh + (2 * DD + t) * DD);
#pragma unroll
        for (int e = 0; e < 16; e++) {
            const float4 a = r0[e], bq = r1[e], c = r2[e];
            whr[2 * e + 0] = (h2){(_Float16)a.x, (_Float16)a.y};
            whr[2 * e + 1] = (h2){(_Float16)a.z, (_Float16)a.w};
            whz[2 * e + 0] = (h2){(_Float16)bq.x, (_Float16)bq.y};
            whz[2 * e + 1] = (h2){(_Float16)bq.z, (_Float16)bq.w};
            whn[2 * e + 0] = (h2){(_Float16)c.x, (_Float16)c.y};
            whn[2 * e + 1] = (h2){(_Float16)c.z, (_Float16)c.w};
        }
    }
#pragma unroll
    for (int i2 = 0; i2 < 32; i2++) {
        asm volatile("" : "+v"(whr[i2]), "+v"(whz[i2]), "+v"(whn[i2]));
    }
    const float br = bhh[t], bz = bhh[DD + t], bn = bhh[2 * DD + t];

    float h = 0.0f;
    h16[t] = (_Float16)0.0f;
    const float* gxr = &gx_lds[0][0];

#pragma unroll 1
    for (int l = 0; l < LL; l++) {
        const float g_r = gxr[t], g_z = gxr[DD + t], g_n = gxr[2 * DD + t];
        float ra0 = 0.f, ra1 = 0.f, ra2 = 0.f, ra3 = 0.f;
        float za0 = 0.f, za1 = 0.f, za2 = 0.f, za3 = 0.f;
        float na0 = 0.f, na1 = 0.f, na2 = 0.f, na3 = 0.f;
#pragma unroll
        for (int j = 0; j < 8; j++) {
            union { float4 f4; h2 hh[4]; } u;
            u.f4 = *(const float4*)&h16[8 * j];   // broadcast (uniform addr)
            ra0 = __builtin_amdgcn_fdot2(u.hh[0], whr[4 * j + 0], ra0, false);
            ra1 = __builtin_amdgcn_fdot2(u.hh[1], whr[4 * j + 1], ra1, false);
            ra2 = __builtin_amdgcn_fdot2(u.hh[2], whr[4 * j + 2], ra2, false);
            ra3 = __builtin_amdgcn_fdot2(u.hh[3], whr[4 * j + 3], ra3, false);
            za0 = __builtin_amdgcn_fdot2(u.hh[0], whz[4 * j + 0], za0, false);
            za1 = __builtin_amdgcn_fdot2(u.hh[1], whz[4 * j + 1], za1, false);
            za2 = __builtin_amdgcn_fdot2(u.hh[2], whz[4 * j + 2], za2, false);
            za3 = __builtin_amdgcn_fdot2(u.hh[3], whz[4 * j + 3], za3, false);
            na0 = __builtin_amdgcn_fdot2(u.hh[0], whn[4 * j + 0], na0, false);
            na1 = __builtin_amdgcn_fdot2(u.hh[1], whn[4 * j + 1], na1, false);
            na2 = __builtin_amdgcn_fdot2(u.hh[2], whn[4 * j + 2], na2, false);
            na3 = __builtin_amdgcn_fdot2(u.hh[3], whn[4 * j + 3], na3, false);
        }
        const float hr = br + ((ra0 + ra1) + (ra2 + ra3));
        const float hz = bz + ((za0 + za1) + (za2 + za3));
        const float hn = bn + ((na0 + na1) + (na2 + na3));

        const float rg = fast_sigmoid(g_r + hr);
        const float zg = fast_sigmoid(g_z + hz);
        const float ng = fast_tanh(g_n + rg * hn);
        h = (1.0f - zg) * ng + zg * h;
        h16[t] = (_Float16)h;   // next iter's broadcast source (own-wave ordering)
        o3[l][t] = h;
        gxr += 192;
    }
    __syncthreads();

    // output-GRU input projections: lane t handles row l=t (3 dots of 64)
    {
        float A0 = obih[0], A1 = obih[1], A2 = obih[2];
        const float* w0 = oWih;
        const float* w1 = oWih + DD;
        const float* w2 = oWih + 2 * DD;
#pragma unroll 8
        for (int e = 0; e < DD; e++) {
            const float ov = o3[t][e];
            A0 = fmaf(ov, w0[e], A0);
            A1 = fmaf(ov, w1[e], A1);
            A2 = fmaf(ov, w2[e], A2);
        }
        gx2[t][0] = A0; gx2[t][1] = A1; gx2[t][2] = A2;
    }
    __syncthreads();

    // H=1 scan (serial, lane 0) with next-step prefetch
    if (t == 0) {
        const float w0 = oWhh[0], w1 = oWhh[1], w2 = oWhh[2];
        const float c0 = obhh[0], c1 = obhh[1], c2 = obhh[2];
        float hh = 0.0f;
        float g0 = gx2[0][0], g1 = gx2[0][1], g2 = gx2[0][2];
#pragma unroll 1
        for (int l = 0; l < LL; l++) {
            const int ln = (l + 1) & 63;
            const float ng0 = gx2[ln][0], ng1 = gx2[ln][1], ng2 = gx2[ln][2];
            const float rg = fast_sigmoid(g0 + fmaf(hh, w0, c0));
            const float zg = fast_sigmoid(g1 + fmaf(hh, w1, c1));
            const float ng = fast_tanh(g2 + rg * fmaf(hh, w2, c2));
            hh = (1.0f - zg) * ng + zg * hh;
            p2[l] = hh;
            g0 = ng0; g1 = ng1; g2 = ng2;
        }
    }
    __syncthreads();

    // bug-faithful mask: col <= max_b(l[b]); wave softmax
    {
        const int maxl = max(max(lvec[0], lvec[1]), max(lvec[2], lvec[3]));
        const float v = (t <= maxl) ? p2[t] : NEG_;
        float mx = v;
        for (int off = 1; off < 64; off <<= 1) mx = fmaxf(mx, __shfl_xor(mx, off, 64));
        const float ex = __expf(v - mx);
        float sum = ex;
        for (int off = 1; off < 64; off <<= 1) sum += __shfl_xor(sum, off, 64);
        p2[t] = ex * rcp_(sum);
    }
    __syncthreads();

    // c[d=t] = sum_l p2[l]*o3[l][t]; publish with agent scope
    {
        float acc = 0.f;
#pragma unroll 8
        for (int l = 0; l < LL; l++) acc = fmaf(p2[l], o3[l][t], acc);
        __hip_atomic_store(&cws[b * DD + t], acc, __ATOMIC_RELAXED, __HIP_MEMORY_SCOPE_AGENT);
    }
    __threadfence();
    if (t == 0) {
        const unsigned int old =
            __hip_atomic_fetch_add(counter, 1u, __ATOMIC_ACQ_REL, __HIP_MEMORY_SCOPE_AGENT);
        is_last = (old == BB - 1) ? 1u : 0u;
    }
    __syncthreads();

    if (is_last) {   // exactly one block; runs the classifier for all batches
        __threadfence();
        float loss = 0.0f;
        for (int bb = 0; bb < BB; bb++) {
            c_lds[t] = __hip_atomic_load(&cws[bb * DD + t], __ATOMIC_RELAXED,
                                         __HIP_MEMORY_SCOPE_AGENT);
            __syncthreads();
            if (t < 32) {
                float a = b1[t];
                const float* wr = W1 + t * DD;
                for (int d = 0; d < DD; d++) a = fmaf(c_lds[d], wr[d], a);
                h1[t] = fmaxf(a, 0.0f);
            }
            __syncthreads();
            if (t < 2) {
                float a = b2[t];
                const float* wr = W2 + t * 32;
                for (int m2 = 0; m2 < 32; m2++) a = fmaf(h1[m2], wr[m2], a);
                lg[t] = a;
            }
            __syncthreads();
            if (t == 0) {
                const float l0 = lg[0], l1 = lg[1];
                const float mx = fmaxf(l0, l1);
                const float e0 = __expf(l0 - mx), e1 = __expf(l1 - mx);
                const float s = e0 + e1;
                out[bb * 2 + 0] = e0 / s;
                out[bb * 2 + 1] = e1 / s;
                const float lp = ((y[bb] == 1) ? l1 : l0) - mx - __logf(s);
                loss -= lp * 0.25f;
            }
            __syncthreads();
        }
        if (t == 0) out[8] = loss;
    }
}

extern "C" void kernel_launch(void* const* d_in, const int* in_sizes, int n_in,
                              void* d_out, int out_size, void* d_ws, size_t ws_size,
                              hipStream_t stream)
{
    const int*   x    = (const int*)d_in[0];
    const int*   y    = (const int*)d_in[1];
    const int*   r    = (const int*)d_in[2];
    const int*   l    = (const int*)d_in[3];
    const float* emb  = (const float*)d_in[4];
    const float* rel  = (const float*)d_in[5];
    const float* aW   = (const float*)d_in[6];
    const float* ab   = (const float*)d_in[7];
    const float* Wih  = (const float*)d_in[8];
    const float* Whh  = (const float*)d_in[9];
    const float* bih  = (const float*)d_in[10];
    const float* bhh  = (const float*)d_in[11];
    const float* oWih = (const float*)d_in[12];
    const float* oWhh = (const float*)d_in[13];
    const float* obih = (const float*)d_in[14];
    const float* obhh = (const float*)d_in[15];
    const float* W1   = (const float*)d_in[16];
    const float* b1   = (const float*)d_in[17];
    const float* W2   = (const float*)d_in[18];
    const float* b2   = (const float*)d_in[19];

    float* ws  = (float*)d_ws;
    float* gx  = ws;                                   // B*L*192 = 49152 floats
    float* cws = ws + 49152;                           // B*D     =   256 floats
    unsigned int* counter = (unsigned int*)(ws + 49152 + 256);

    attn_kernel<<<dim3(LL, BB), 256, 0, stream>>>(x, r, emb, rel, aW, ab, Wih, bih,
                                                  gx, counter);
    gru_kernel<<<BB, 64, 0, stream>>>(gx, Whh, bhh, oWih, oWhh, obih, obhh, l, cws,
                                      counter, y, W1, b1, W2, b2, (float*)d_out);
}

// Round 7
// 54.045 us; speedup vs baseline: 1.7478x; 1.0111x over previous
//
#include <hip/hip_runtime.h>
#include <math.h>

#define BB 4
#define LL 64
#define DD 64
#define NEG_ -1e9f

typedef _Float16 h2 __attribute__((ext_vector_type(2)));

__device__ __forceinline__ float rcp_(float x) { return __builtin_amdgcn_rcpf(x); }
__device__ __forceinline__ float fast_sigmoid(float x) { return rcp_(1.0f + __expf(-x)); }
// tanh(x) = 1 - 2/(exp(2x)+1); saturates correctly via exp->inf/0, rcp(inf)=0
__device__ __forceinline__ float fast_tanh(float x) { return fmaf(-2.0f, rcp_(__expf(2.0f * x) + 1.0f), 1.0f); }

// 4-wave attn: w-phase split over waves (k) and lanes (e-quad x d-offset) with
// float4 rel loads + shfl_xor d-reduce. Then scores/softmax (wave0), PV (all
// waves), out-proj + gx-proj (all 256 threads). Also zeroes the gru/cls counter.
__global__ __launch_bounds__(256) void attn_kernel(
    const int* __restrict__ x, const int* __restrict__ r,
    const float* __restrict__ emb, const float* __restrict__ rel,
    const float* __restrict__ aW, const float* __restrict__ ab,
    const float* __restrict__ Wih, const float* __restrict__ bih,
    float* __restrict__ gx, unsigned int* __restrict__ counter)
{
    const int i = blockIdx.x, b = blockIdx.y;
    const int tt = threadIdx.x, lane = tt & 63, wv = tt >> 6;
    __shared__ float o_lds[LL][DD + 1];
    __shared__ float w_lds[16][DD + 1];
    __shared__ float p_lds[LL];
    __shared__ float pv_part[4][DD];
    __shared__ float ao_lds[DD];
    __shared__ float o2_lds[DD];

    if (i == 0 && b == 0 && tt == 0) *counter = 0;   // handoff counter for gru+cls

    // stage o: thread covers row j=tt>>2, floats q*16..q*16+15 (coalesced float4)
    {
        const int j = tt >> 2, q = tt & 3;
        const int row = x[b * LL + j];
        const float4* src = (const float4*)(emb + row * DD + q * 16);
        const float4 v0 = src[0], v1 = src[1], v2 = src[2], v3 = src[3];
        float* dst = &o_lds[j][q * 16];
        dst[0] = v0.x; dst[1] = v0.y; dst[2] = v0.z; dst[3] = v0.w;
        dst[4] = v1.x; dst[5] = v1.y; dst[6] = v1.z; dst[7] = v1.w;
        dst[8] = v2.x; dst[9] = v2.y; dst[10] = v2.z; dst[11] = v2.w;
        dst[12] = v3.x; dst[13] = v3.y; dst[14] = v3.z; dst[15] = v3.w;
    }
    __syncthreads();

    // w-phase: wave wv handles k = wv*4+1 .. wv*4+4 (<=15).
    // lane = (dq=lane>>4, eq=lane&15): partial over d in {g*4+dq}, e-range eq*4..+3
    {
        const int eq = lane & 15, dq = lane >> 4;
#pragma unroll
        for (int kk = 0; kk < 4; kk++) {
            const int k = wv * 4 + kk + 1;
            if (k <= 15) {
                float4 acc = make_float4(0.f, 0.f, 0.f, 0.f);
                const float* relb = rel + k * 4096 + eq * 4;
#pragma unroll
                for (int g2 = 0; g2 < 16; g2++) {
                    const int d = g2 * 4 + dq;
                    const float od = o_lds[i][d];
                    const float4 rv4 = *(const float4*)(relb + d * 64);
                    acc.x = fmaf(od, rv4.x, acc.x);
                    acc.y = fmaf(od, rv4.y, acc.y);
                    acc.z = fmaf(od, rv4.z, acc.z);
                    acc.w = fmaf(od, rv4.w, acc.w);
                }
                acc.x += __shfl_xor(acc.x, 16, 64); acc.y += __shfl_xor(acc.y, 16, 64);
                acc.z += __shfl_xor(acc.z, 16, 64); acc.w += __shfl_xor(acc.w, 16, 64);
                acc.x += __shfl_xor(acc.x, 32, 64); acc.y += __shfl_xor(acc.y, 32, 64);
                acc.z += __shfl_xor(acc.z, 32, 64); acc.w += __shfl_xor(acc.w, 32, 64);
                if (dq == 0) {
                    float* wd = &w_lds[k][eq * 4];
                    wd[0] = acc.x; wd[1] = acc.y; wd[2] = acc.z; wd[3] = acc.w;
                }
            }
        }
    }
    __syncthreads();

    // scores + softmax over j: wave 0 (lane = j)
    if (wv == 0) {
        const int rv = r[(b * LL + i) * LL + lane];
        float s = NEG_;
        if (rv > 0) {
            float a0 = 0.f, a1 = 0.f;
#pragma unroll
            for (int e = 0; e < DD; e += 2) {
                a0 = fmaf(w_lds[rv][e + 0], o_lds[lane][e + 0], a0);
                a1 = fmaf(w_lds[rv][e + 1], o_lds[lane][e + 1], a1);
            }
            s = a0 + a1;
        }
        float mx = s;
        for (int off = 1; off < 64; off <<= 1) mx = fmaxf(mx, __shfl_xor(mx, off, 64));
        const float ex = __expf(s - mx);
        float sum = ex;
        for (int off = 1; off < 64; off <<= 1) sum += __shfl_xor(sum, off, 64);
        p_lds[lane] = ex * rcp_(sum);
    }
    __syncthreads();

    // PV: wave wv sums its 16 j's; lane = d
    {
        float acc = 0.f;
#pragma unroll
        for (int j = 0; j < 16; j++) {
            const int jj = wv * 16 + j;
            acc = fmaf(p_lds[jj], o_lds[jj][lane], acc);
        }
        pv_part[wv][lane] = acc;
    }
    __syncthreads();
    if (wv == 0)
        ao_lds[lane] = (pv_part[0][lane] + pv_part[1][lane]) + (pv_part[2][lane] + pv_part[3][lane]);
    __syncthreads();

    // o2: 4 threads per output row (row=tt>>2, q=tt&3 covers e=q*16..+15)
    {
        const int row = tt >> 2, q = tt & 3;
        float a = 0.f;
        const float4* wr4 = (const float4*)(aW + row * DD + q * 16);
#pragma unroll
        for (int e4 = 0; e4 < 4; e4++) {
            const float4 w4 = wr4[e4];
            const float* av = &ao_lds[q * 16 + e4 * 4];
            a = fmaf(av[0], w4.x, a); a = fmaf(av[1], w4.y, a);
            a = fmaf(av[2], w4.z, a); a = fmaf(av[3], w4.w, a);
        }
        a += __shfl_xor(a, 1, 64);
        a += __shfl_xor(a, 2, 64);
        if (q == 0) o2_lds[row] = a + ab[row];
    }
    __syncthreads();

    // gx: threads 0..191, g = tt: gx[g] = sum_e o2[e]*Wih[g,e] + bih[g]
    if (tt < 192) {
        float a = bih[tt];
        const float4* wg4 = (const float4*)(Wih + tt * DD);
#pragma unroll 4
        for (int e4 = 0; e4 < 16; e4++) {
            const float4 w4 = wg4[e4];
            const float* ov = &o2_lds[e4 * 4];
            a = fmaf(ov[0], w4.x, a); a = fmaf(ov[1], w4.y, a);
            a = fmaf(ov[2], w4.z, a); a = fmaf(ov[3], w4.w, a);
        }
        gx[(b * LL + i) * 192 + tt] = a;
    }
}

// ONE WAVE per batch, barrier-free scan. Whh as 96 packed-f16 VGPRs,
// v_dot2_f32_f16 dots, f16 h broadcast via LDS. R7: union type-pun replaced
// with __builtin_bit_cast (register-guaranteed; the union could be demoted to
// scratch -> 8 dependent scratch round-trips per serial step). Last block
// (device-scope atomic counter) runs the classifier inline.
__global__ __launch_bounds__(64, 1) void gru_kernel(
    const float* __restrict__ gx, const float* __restrict__ Whh, const float* __restrict__ bhh,
    const float* __restrict__ oWih, const float* __restrict__ oWhh,
    const float* __restrict__ obih, const float* __restrict__ obhh,
    const int* __restrict__ lvec, float* __restrict__ cws,
    unsigned int* __restrict__ counter, const int* __restrict__ y,
    const float* __restrict__ W1, const float* __restrict__ b1,
    const float* __restrict__ W2, const float* __restrict__ b2,
    float* __restrict__ out)
{
    const int b = blockIdx.x, t = threadIdx.x;
    __shared__ float gx_lds[LL][192];      // 48 KB flat
    __shared__ _Float16 h16[DD] __attribute__((aligned(16)));
    __shared__ float o3[LL][DD + 1];
    __shared__ float gx2[LL][4];
    __shared__ float p2[LL];
    __shared__ float c_lds[DD];
    __shared__ float h1[32];
    __shared__ float lg[2];
    __shared__ unsigned int is_last;

    // stage gx (this batch): 3072 float4 over 64 lanes = 48 each, coalesced
    {
        const float4* src = (const float4*)(gx + b * LL * 192);
        float4* dst = (float4*)&gx_lds[0][0];
#pragma unroll 4
        for (int f = 0; f < 48; f++) dst[f * 64 + t] = src[f * 64 + t];
    }

    // Whh rows t (r), 64+t (z), 128+t (n) as 32 packed-f16 pairs each
    h2 whr[32], whz[32], whn[32];
    {
        const float4* r0 = (const float4*)(Whh + t * DD);
        const float4* r1 = (const float4*)(Whh + (DD + t) * DD);
        const float4* r2 = (const float4*)(Whh + (2 * DD + t) * DD);
#pragma unroll
        for (int e = 0; e < 16; e++) {
            const float4 a = r0[e], bq = r1[e], c = r2[e];
            whr[2 * e + 0] = (h2){(_Float16)a.x, (_Float16)a.y};
            whr[2 * e + 1] = (h2){(_Float16)a.z, (_Float16)a.w};
            whz[2 * e + 0] = (h2){(_Float16)bq.x, (_Float16)bq.y};
            whz[2 * e + 1] = (h2){(_Float16)bq.z, (_Float16)bq.w};
            whn[2 * e + 0] = (h2){(_Float16)c.x, (_Float16)c.y};
            whn[2 * e + 1] = (h2){(_Float16)c.z, (_Float16)c.w};
        }
    }
#pragma unroll
    for (int i2 = 0; i2 < 32; i2++) {
        asm volatile("" : "+v"(whr[i2]), "+v"(whz[i2]), "+v"(whn[i2]));
    }
    const float br = bhh[t], bz = bhh[DD + t], bn = bhh[2 * DD + t];

    float h = 0.0f;
    h16[t] = (_Float16)0.0f;
    const float* gxr = &gx_lds[0][0];

#pragma unroll 1
    for (int l = 0; l < LL; l++) {
        const float g_r = gxr[t], g_z = gxr[DD + t], g_n = gxr[2 * DD + t];
        float ra0 = 0.f, ra1 = 0.f, ra2 = 0.f, ra3 = 0.f;
        float za0 = 0.f, za1 = 0.f, za2 = 0.f, za3 = 0.f;
        float na0 = 0.f, na1 = 0.f, na2 = 0.f, na3 = 0.f;
#pragma unroll
        for (int j = 0; j < 8; j++) {
            const float4 f = *(const float4*)&h16[8 * j];   // uniform broadcast
            const h2 p0 = __builtin_bit_cast(h2, f.x);       // register bitcast,
            const h2 p1 = __builtin_bit_cast(h2, f.y);       // no memory object
            const h2 p2_ = __builtin_bit_cast(h2, f.z);
            const h2 p3 = __builtin_bit_cast(h2, f.w);
            ra0 = __builtin_amdgcn_fdot2(p0, whr[4 * j + 0], ra0, false);
            ra1 = __builtin_amdgcn_fdot2(p1, whr[4 * j + 1], ra1, false);
            ra2 = __builtin_amdgcn_fdot2(p2_, whr[4 * j + 2], ra2, false);
            ra3 = __builtin_amdgcn_fdot2(p3, whr[4 * j + 3], ra3, false);
            za0 = __builtin_amdgcn_fdot2(p0, whz[4 * j + 0], za0, false);
            za1 = __builtin_amdgcn_fdot2(p1, whz[4 * j + 1], za1, false);
            za2 = __builtin_amdgcn_fdot2(p2_, whz[4 * j + 2], za2, false);
            za3 = __builtin_amdgcn_fdot2(p3, whz[4 * j + 3], za3, false);
            na0 = __builtin_amdgcn_fdot2(p0, whn[4 * j + 0], na0, false);
            na1 = __builtin_amdgcn_fdot2(p1, whn[4 * j + 1], na1, false);
            na2 = __builtin_amdgcn_fdot2(p2_, whn[4 * j + 2], na2, false);
            na3 = __builtin_amdgcn_fdot2(p3, whn[4 * j + 3], na3, false);
        }
        const float hr = br + ((ra0 + ra1) + (ra2 + ra3));
        const float hz = bz + ((za0 + za1) + (za2 + za3));
        const float hn = bn + ((na0 + na1) + (na2 + na3));

        const float rg = fast_sigmoid(g_r + hr);
        const float zg = fast_sigmoid(g_z + hz);
        const float ng = fast_tanh(g_n + rg * hn);
        h = (1.0f - zg) * ng + zg * h;
        h16[t] = (_Float16)h;   // next iter's broadcast source (own-wave ordering)
        o3[l][t] = h;
        gxr += 192;
    }
    __syncthreads();

    // output-GRU input projections: lane t handles row l=t (3 dots of 64)
    {
        float A0 = obih[0], A1 = obih[1], A2 = obih[2];
        const float* w0 = oWih;
        const float* w1 = oWih + DD;
        const float* w2 = oWih + 2 * DD;
#pragma unroll 8
        for (int e = 0; e < DD; e++) {
            const float ov = o3[t][e];
            A0 = fmaf(ov, w0[e], A0);
            A1 = fmaf(ov, w1[e], A1);
            A2 = fmaf(ov, w2[e], A2);
        }
        gx2[t][0] = A0; gx2[t][1] = A1; gx2[t][2] = A2;
    }
    __syncthreads();

    // H=1 scan (serial, lane 0) with next-step prefetch
    if (t == 0) {
        const float w0 = oWhh[0], w1 = oWhh[1], w2 = oWhh[2];
        const float c0 = obhh[0], c1 = obhh[1], c2 = obhh[2];
        float hh = 0.0f;
        float g0 = gx2[0][0], g1 = gx2[0][1], g2 = gx2[0][2];
#pragma unroll 1
        for (int l = 0; l < LL; l++) {
            const int ln = (l + 1) & 63;
            const float ng0 = gx2[ln][0], ng1 = gx2[ln][1], ng2 = gx2[ln][2];
            const float rg = fast_sigmoid(g0 + fmaf(hh, w0, c0));
            const float zg = fast_sigmoid(g1 + fmaf(hh, w1, c1));
            const float ng = fast_tanh(g2 + rg * fmaf(hh, w2, c2));
            hh = (1.0f - zg) * ng + zg * hh;
            p2[l] = hh;
            g0 = ng0; g1 = ng1; g2 = ng2;
        }
    }
    __syncthreads();

    // bug-faithful mask: col <= max_b(l[b]); wave softmax
    {
        const int maxl = max(max(lvec[0], lvec[1]), max(lvec[2], lvec[3]));
        const float v = (t <= maxl) ? p2[t] : NEG_;
        float mx = v;
        for (int off = 1; off < 64; off <<= 1) mx = fmaxf(mx, __shfl_xor(mx, off, 64));
        const float ex = __expf(v - mx);
        float sum = ex;
        for (int off = 1; off < 64; off <<= 1) sum += __shfl_xor(sum, off, 64);
        p2[t] = ex * rcp_(sum);
    }
    __syncthreads();

    // c[d=t] = sum_l p2[l]*o3[l][t]; publish with agent scope
    {
        float acc = 0.f;
#pragma unroll 8
        for (int l = 0; l < LL; l++) acc = fmaf(p2[l], o3[l][t], acc);
        __hip_atomic_store(&cws[b * DD + t], acc, __ATOMIC_RELAXED, __HIP_MEMORY_SCOPE_AGENT);
    }
    __threadfence();
    if (t == 0) {
        const unsigned int old =
            __hip_atomic_fetch_add(counter, 1u, __ATOMIC_ACQ_REL, __HIP_MEMORY_SCOPE_AGENT);
        is_last = (old == BB - 1) ? 1u : 0u;
    }
    __syncthreads();

    if (is_last) {   // exactly one block; runs the classifier for all batches
        __threadfence();
        float loss = 0.0f;
        for (int bb = 0; bb < BB; bb++) {
            c_lds[t] = __hip_atomic_load(&cws[bb * DD + t], __ATOMIC_RELAXED,
                                         __HIP_MEMORY_SCOPE_AGENT);
            __syncthreads();
            if (t < 32) {
                float a = b1[t];
                const float* wr = W1 + t * DD;
                for (int d = 0; d < DD; d++) a = fmaf(c_lds[d], wr[d], a);
                h1[t] = fmaxf(a, 0.0f);
            }
            __syncthreads();
            if (t < 2) {
                float a = b2[t];
                const float* wr = W2 + t * 32;
                for (int m2 = 0; m2 < 32; m2++) a = fmaf(h1[m2], wr[m2], a);
                lg[t] = a;
            }
            __syncthreads();
            if (t == 0) {
                const float l0 = lg[0], l1 = lg[1];
                const float mx = fmaxf(l0, l1);
                const float e0 = __expf(l0 - mx), e1 = __expf(l1 - mx);
                const float s = e0 + e1;
                out[bb * 2 + 0] = e0 / s;
                out[bb * 2 + 1] = e1 / s;
                const float lp = ((y[bb] == 1) ? l1 : l0) - mx - __logf(s);
                loss -= lp * 0.25f;
            }
            __syncthreads();
        }
        if (t == 0) out[8] = loss;
    }
}

extern "C" void kernel_launch(void* const* d_in, const int* in_sizes, int n_in,
                              void* d_out, int out_size, void* d_ws, size_t ws_size,
                              hipStream_t stream)
{
    const int*   x    = (const int*)d_in[0];
    const int*   y    = (const int*)d_in[1];
    const int*   r    = (const int*)d_in[2];
    const int*   l    = (const int*)d_in[3];
    const float* emb  = (const float*)d_in[4];
    const float* rel  = (const float*)d_in[5];
    const float* aW   = (const float*)d_in[6];
    const float* ab   = (const float*)d_in[7];
    const float* Wih  = (const float*)d_in[8];
    const float* Whh  = (const float*)d_in[9];
    const float* bih  = (const float*)d_in[10];
    const float* bhh  = (const float*)d_in[11];
    const float* oWih = (const float*)d_in[12];
    const float* oWhh = (const float*)d_in[13];
    const float* obih = (const float*)d_in[14];
    const float* obhh = (const float*)d_in[15];
    const float* W1   = (const float*)d_in[16];
    const float* b1   = (const float*)d_in[17];
    const float* W2   = (const float*)d_in[18];
    const float* b2   = (const float*)d_in[19];

    float* ws  = (float*)d_ws;
    float* gx  = ws;                                   // B*L*192 = 49152 floats
    float* cws = ws + 49152;                           // B*D     =   256 floats
    unsigned int* counter = (unsigned int*)(ws + 49152 + 256);

    attn_kernel<<<dim3(LL, BB), 256, 0, stream>>>(x, r, emb, rel, aW, ab, Wih, bih,
                                                  gx, counter);
    gru_kernel<<<BB, 64, 0, stream>>>(gx, Whh, bhh, oWih, oWhh, obih, obhh, l, cws,
                                      counter, y, W1, b1, W2, b2, (float*)d_out);
}